// Round 2
// baseline (1621.263 us; speedup 1.0000x reference)
//
#include <hip/hip_runtime.h>

// N=1024, D=16, H=32, 3H=96.  All tensors fp32 (per reference dtypes).

// ---------------------------------------------------------------------------
// K1: stage-1 pairwise split.  A[i,h] = sum_d (w[h,d]-w[h,16+d])*x[i,d] + b[h]
//                              B[j,h] = sum_d w[h,16+d]*x[j,d]
// relu(A[i,:]+B[j,:]) reconstructs out1[i,j,:] -- the [N,N,H] tensor is never
// materialized (rank-separable linear layer).
// ---------------------------------------------------------------------------
__global__ void proj1_kernel(const float* __restrict__ x, const float* __restrict__ w,
                             const float* __restrict__ bias,
                             float* __restrict__ A, float* __restrict__ B) {
    int idx = blockIdx.x * 256 + threadIdx.x;      // 0..32767
    int i = idx >> 5, h = idx & 31;
    float sa = bias[h];
    float sb = 0.f;
#pragma unroll
    for (int d = 0; d < 16; ++d) {
        float xv = x[i * 16 + d];
        float wa = w[h * 32 + d];
        float wb = w[h * 32 + 16 + d];
        sa += (wa - wb) * xv;
        sb += wb * xv;
    }
    A[i * 32 + h] = sa;
    B[i * 32 + h] = sb;
}

// ---------------------------------------------------------------------------
// K3: stage-2 pairwise split, input h1 [1024,32] fp32, w: [32,64] fp32
// ---------------------------------------------------------------------------
__global__ void proj2_kernel(const float* __restrict__ h1, const float* __restrict__ w,
                             const float* __restrict__ bias,
                             float* __restrict__ A, float* __restrict__ B) {
    int idx = blockIdx.x * 256 + threadIdx.x;      // 0..32767
    int i = idx >> 5, h = idx & 31;
    float sa = bias[h];
    float sb = 0.f;
#pragma unroll
    for (int k = 0; k < 32; ++k) {
        float hv = h1[i * 32 + k];
        float wa = w[h * 64 + k];
        float wb = w[h * 64 + 32 + k];
        sa += (wa - wb) * hv;
        sb += wb * hv;
    }
    A[i * 32 + h] = sa;
    B[i * 32 + h] = sb;
}

// ---------------------------------------------------------------------------
// GRU: one block per batch element b. seq[b,t,:] = relu(A[b,:] + B[t,:]).
// Gate order r,z,n (PyTorch). 96 gate threads, each owns its wih/whh row in
// registers (64 VGPRs). h kept in LDS; 2 barriers per step.
// ---------------------------------------------------------------------------
__global__ __launch_bounds__(128) void gru_kernel(
    const float* __restrict__ A, const float* __restrict__ B,
    const float* __restrict__ wih, const float* __restrict__ whh,
    const float* __restrict__ bih, const float* __restrict__ bhh,
    float* __restrict__ h_out) {
    const int b = blockIdx.x;
    const int g = threadIdx.x;                     // 0..127 (96 active for dots)

    __shared__ __align__(16) float o_s[32];
    __shared__ __align__(16) float h_s[32];
    __shared__ float gx_s[96];
    __shared__ float gh_s[96];

    float wih_r[32], whh_r[32];
    float xb = 0.f, hb = 0.f;
    if (g < 96) {
#pragma unroll
        for (int k = 0; k < 32; ++k) {
            wih_r[k] = wih[g * 32 + k];
            whh_r[k] = whh[g * 32 + k];
        }
        xb = bih[g];
        hb = bhh[g];
    }
    float a_r = 0.f, b_cur = 0.f;
    if (g < 32) {
        a_r = A[b * 32 + g];
        b_cur = B[g];
        h_s[g] = 0.f;
    }

    for (int t = 0; t < 1024; ++t) {
        if (g < 32) o_s[g] = fmaxf(a_r + b_cur, 0.f);
        __syncthreads();                            // o_s, h_s ready
        if (g < 32 && t < 1023) b_cur = B[(t + 1) * 32 + g];  // prefetch
        if (g < 96) {
            float xg = xb, hg = hb;
            const float4* o4 = (const float4*)o_s;
            const float4* h4 = (const float4*)h_s;
#pragma unroll
            for (int k = 0; k < 8; ++k) {
                float4 ov = o4[k];
                float4 hv = h4[k];
                xg += wih_r[4 * k + 0] * ov.x + wih_r[4 * k + 1] * ov.y +
                      wih_r[4 * k + 2] * ov.z + wih_r[4 * k + 3] * ov.w;
                hg += whh_r[4 * k + 0] * hv.x + whh_r[4 * k + 1] * hv.y +
                      whh_r[4 * k + 2] * hv.z + whh_r[4 * k + 3] * hv.w;
            }
            gx_s[g] = xg;
            gh_s[g] = hg;
        }
        __syncthreads();                            // gates ready
        if (g < 32) {
            float r = 1.f / (1.f + __expf(-(gx_s[g] + gh_s[g])));
            float z = 1.f / (1.f + __expf(-(gx_s[g + 32] + gh_s[g + 32])));
            float pre = gx_s[g + 64] + r * gh_s[g + 64];
            float n = 1.f - 2.f / (__expf(2.f * pre) + 1.f);
            float hn = (1.f - z) * n + z * h_s[g];
            h_s[g] = hn;
            if (t == 1023) h_out[b * 32 + g] = hn;
        }
        // next iteration's first barrier orders the h_s write vs. dot reads
    }
}

// ---------------------------------------------------------------------------
// K5: classifier. out[i,o] = sum_k clf_w[o,k]*h2[i,k] + clf_b[o]  (fp32 out)
// ---------------------------------------------------------------------------
__global__ void clf_kernel(const float* __restrict__ h2, const float* __restrict__ w,
                           const float* __restrict__ bias, float* __restrict__ out) {
    int idx = blockIdx.x * 256 + threadIdx.x;      // 0..3071
    if (idx >= 3072) return;
    int i = idx / 3, o = idx - i * 3;
    float s = bias[o];
#pragma unroll
    for (int k = 0; k < 32; ++k) s += w[o * 32 + k] * h2[i * 32 + k];
    out[idx] = s;
}

extern "C" void kernel_launch(void* const* d_in, const int* in_sizes, int n_in,
                              void* d_out, int out_size, void* d_ws, size_t ws_size,
                              hipStream_t stream) {
    const float* x       = (const float*)d_in[0];
    const float* p1w     = (const float*)d_in[1];
    const float* p1b     = (const float*)d_in[2];
    const float* g1_wih  = (const float*)d_in[3];
    const float* g1_whh  = (const float*)d_in[4];
    const float* g1_bih  = (const float*)d_in[5];
    const float* g1_bhh  = (const float*)d_in[6];
    const float* p2w     = (const float*)d_in[7];
    const float* p2b     = (const float*)d_in[8];
    const float* g2_wih  = (const float*)d_in[9];
    const float* g2_whh  = (const float*)d_in[10];
    const float* g2_bih  = (const float*)d_in[11];
    const float* g2_bhh  = (const float*)d_in[12];
    const float* clfw    = (const float*)d_in[13];
    const float* clfb    = (const float*)d_in[14];

    // Workspace layout (reused across stages; 3 x 32768 floats = 384 KB):
    float* ws = (float*)d_ws;
    float* A  = ws;              // A1 then A2
    float* Bt = ws + 32768;      // B1 then B2
    float* h  = ws + 65536;      // h1 then h2

    proj1_kernel<<<128, 256, 0, stream>>>(x, p1w, p1b, A, Bt);
    gru_kernel<<<1024, 128, 0, stream>>>(A, Bt, g1_wih, g1_whh, g1_bih, g1_bhh, h);
    proj2_kernel<<<128, 256, 0, stream>>>(h, p2w, p2b, A, Bt);
    gru_kernel<<<1024, 128, 0, stream>>>(A, Bt, g2_wih, g2_whh, g2_bih, g2_bhh, h);
    clf_kernel<<<12, 256, 0, stream>>>(h, clfw, clfb, (float*)d_out);
}

// Round 3
// 1384.645 us; speedup vs baseline: 1.1709x; 1.1709x over previous
//
#include <hip/hip_runtime.h>

// N=1024, D=16, H=32, 3H=96.  All tensors fp32 (per reference dtypes).

__device__ __forceinline__ float rl(float v, int k) {
    return __int_as_float(__builtin_amdgcn_readlane(__float_as_int(v), k));
}

// ---------------------------------------------------------------------------
// K1: stage-1 pairwise split.  A[i,h] = sum_d (w[h,d]-w[h,16+d])*x[i,d] + b[h]
//                              B[j,h] = sum_d w[h,16+d]*x[j,d]
// relu(A[i,:]+B[j,:]) reconstructs out1[i,j,:] -- the [N,N,H] tensor is never
// materialized (rank-separable linear layer).
// ---------------------------------------------------------------------------
__global__ void proj1_kernel(const float* __restrict__ x, const float* __restrict__ w,
                             const float* __restrict__ bias,
                             float* __restrict__ A, float* __restrict__ B) {
    int idx = blockIdx.x * 256 + threadIdx.x;      // 0..32767
    int i = idx >> 5, h = idx & 31;
    float sa = bias[h];
    float sb = 0.f;
#pragma unroll
    for (int d = 0; d < 16; ++d) {
        float xv = x[i * 16 + d];
        float wa = w[h * 32 + d];
        float wb = w[h * 32 + 16 + d];
        sa += (wa - wb) * xv;
        sb += wb * xv;
    }
    A[i * 32 + h] = sa;
    B[i * 32 + h] = sb;
}

// ---------------------------------------------------------------------------
// K3: stage-2 pairwise split, input h1 [1024,32] fp32, w: [32,64] fp32
// ---------------------------------------------------------------------------
__global__ void proj2_kernel(const float* __restrict__ h1, const float* __restrict__ w,
                             const float* __restrict__ bias,
                             float* __restrict__ A, float* __restrict__ B) {
    int idx = blockIdx.x * 256 + threadIdx.x;      // 0..32767
    int i = idx >> 5, h = idx & 31;
    float sa = bias[h];
    float sb = 0.f;
#pragma unroll
    for (int k = 0; k < 32; ++k) {
        float hv = h1[i * 32 + k];
        float wa = w[h * 64 + k];
        float wb = w[h * 64 + 32 + k];
        sa += (wa - wb) * hv;
        sb += wb * hv;
    }
    A[i * 32 + h] = sa;
    B[i * 32 + h] = sb;
}

// ---------------------------------------------------------------------------
// GRU: ONE WAVE per batch element. Wave-synchronous, no LDS, no barriers.
// seq[b,t,:] = relu(A[b,:] + B[t,:]).  Gate order r,z,n (PyTorch).
//
// Lane mapping (l = threadIdx.x, m = l&31):
//   fused gate row = l  (rows 0..31 = r, rows 32..63 = z): dot over BOTH
//     o (input) and h (hidden) parts -> full r/z pre-activation per lane.
//   n-gate split: lanes <32 compute hn_m (whh row 64+m over h, + bhh),
//                 lanes >=32 compute xn_m (wih row 64+m over o, + bih).
// o and h are wave-uniform 32-vectors: extracted to SGPRs via v_readlane and
// used as the scalar operand of v_fmac (1 SGPR read per VALU op -- legal).
// ---------------------------------------------------------------------------
__global__ __launch_bounds__(64) void gru_kernel(
    const float* __restrict__ A, const float* __restrict__ B,
    const float* __restrict__ wih, const float* __restrict__ whh,
    const float* __restrict__ bih, const float* __restrict__ bhh,
    float* __restrict__ h_out) {
    const int b = blockIdx.x;
    const int l = threadIdx.x;        // 0..63
    const int m = l & 31;
    const bool lo = (l < 32);

    // --- weight rows into registers (96 VGPRs) ---
    float wf_ih[32], wf_hh[32], w2[32];
#pragma unroll
    for (int k = 0; k < 32; ++k) {
        wf_ih[k] = wih[l * 32 + k];
        wf_hh[k] = whh[l * 32 + k];
    }
    const float* w2src = lo ? whh : wih;           // hn row | xn row
#pragma unroll
    for (int k = 0; k < 32; ++k) w2[k] = w2src[(64 + m) * 32 + k];

    const float bias1 = bih[l] + bhh[l];           // fused r/z bias
    const float bias2 = lo ? bhh[64 + m] : bih[64 + m];

    float a_r   = lo ? A[b * 32 + m] : 0.f;
    float b_cur = lo ? B[m] : 0.f;
    float h_l = 0.f;                               // h_m lives in lane m (<32)

    float hu[32];                                  // wave-uniform h (SGPRs)
#pragma unroll
    for (int k = 0; k < 32; ++k) hu[k] = 0.f;

#pragma unroll 2
    for (int t = 0; t < 1024; ++t) {
        // o_t = relu(A + B[t])   (meaningful in lanes <32)
        float o_l = fmaxf(a_r + b_cur, 0.f);
        if (lo) b_cur = B[((t + 1) & 1023) * 32 + m];   // prefetch next B row

        // broadcast o to SGPRs
        float ou[32];
#pragma unroll
        for (int k = 0; k < 32; ++k) ou[k] = rl(o_l, k);

        // fused r/z dot: split into two 32-deep chains for ILP
        float acc_o = bias1, acc_h = 0.f;
#pragma unroll
        for (int k = 0; k < 32; ++k) acc_o = fmaf(wf_ih[k], ou[k], acc_o);
#pragma unroll
        for (int k = 0; k < 32; ++k) acc_h = fmaf(wf_hh[k], hu[k], acc_h);

        // n-gate half dot (divergent halves; each 32 fmac w/ SGPR operand)
        float acc2 = bias2;
        if (lo) {
#pragma unroll
            for (int k = 0; k < 32; ++k) acc2 = fmaf(w2[k], hu[k], acc2);  // hn
        } else {
#pragma unroll
            for (int k = 0; k < 32; ++k) acc2 = fmaf(w2[k], ou[k], acc2);  // xn
        }

        // r (lanes<32) / z (lanes>=32)
        float g1 = acc_o + acc_h;
        float sg = 1.f / (1.f + __expf(-g1));

        // stitch halves: xn and z down to lanes <32
        float xn = __shfl(acc2, l + 32);   // lanes<32: xn_m  (upper: junk)
        float zz = __shfl(sg,   l + 32);   // lanes<32: z_m   (upper: junk)

        // n = tanh(xn + r*hn); h' = (1-z)*n + z*h   (valid in lanes<32)
        float npre = xn + sg * acc2;
        float e = __expf(2.f * npre);
        float n = 1.f - 2.f / (e + 1.f);
        float hn_new = (1.f - zz) * n + zz * h_l;
        if (lo) h_l = hn_new;

        // broadcast new h to SGPRs for next step
#pragma unroll
        for (int k = 0; k < 32; ++k) hu[k] = rl(h_l, k);
    }

    if (lo) h_out[b * 32 + m] = h_l;
}

// ---------------------------------------------------------------------------
// K5: classifier. out[i,o] = sum_k clf_w[o,k]*h2[i,k] + clf_b[o]  (fp32 out)
// ---------------------------------------------------------------------------
__global__ void clf_kernel(const float* __restrict__ h2, const float* __restrict__ w,
                           const float* __restrict__ bias, float* __restrict__ out) {
    int idx = blockIdx.x * 256 + threadIdx.x;      // 0..3071
    if (idx >= 3072) return;
    int i = idx / 3, o = idx - i * 3;
    float s = bias[o];
#pragma unroll
    for (int k = 0; k < 32; ++k) s += w[o * 32 + k] * h2[i * 32 + k];
    out[idx] = s;
}

extern "C" void kernel_launch(void* const* d_in, const int* in_sizes, int n_in,
                              void* d_out, int out_size, void* d_ws, size_t ws_size,
                              hipStream_t stream) {
    const float* x       = (const float*)d_in[0];
    const float* p1w     = (const float*)d_in[1];
    const float* p1b     = (const float*)d_in[2];
    const float* g1_wih  = (const float*)d_in[3];
    const float* g1_whh  = (const float*)d_in[4];
    const float* g1_bih  = (const float*)d_in[5];
    const float* g1_bhh  = (const float*)d_in[6];
    const float* p2w     = (const float*)d_in[7];
    const float* p2b     = (const float*)d_in[8];
    const float* g2_wih  = (const float*)d_in[9];
    const float* g2_whh  = (const float*)d_in[10];
    const float* g2_bih  = (const float*)d_in[11];
    const float* g2_bhh  = (const float*)d_in[12];
    const float* clfw    = (const float*)d_in[13];
    const float* clfb    = (const float*)d_in[14];

    // Workspace layout (reused across stages; 3 x 32768 floats = 384 KB):
    float* ws = (float*)d_ws;
    float* A  = ws;              // A1 then A2
    float* Bt = ws + 32768;      // B1 then B2
    float* h  = ws + 65536;      // h1 then h2

    proj1_kernel<<<128, 256, 0, stream>>>(x, p1w, p1b, A, Bt);
    gru_kernel<<<1024, 64, 0, stream>>>(A, Bt, g1_wih, g1_whh, g1_bih, g1_bhh, h);
    proj2_kernel<<<128, 256, 0, stream>>>(h, p2w, p2b, A, Bt);
    gru_kernel<<<1024, 64, 0, stream>>>(A, Bt, g2_wih, g2_whh, g2_bih, g2_bhh, h);
    clf_kernel<<<12, 256, 0, stream>>>(h, clfw, clfb, (float*)d_out);
}

// Round 4
// 957.541 us; speedup vs baseline: 1.6932x; 1.4460x over previous
//
#include <hip/hip_runtime.h>

// N=1024, D=16, H=32, 3H=96.  All tensors fp32 (per reference dtypes).

__device__ __forceinline__ float rl(float v, int k) {
    return __int_as_float(__builtin_amdgcn_readlane(__float_as_int(v), k));
}

// ---------------------------------------------------------------------------
// K1: stage-1 pairwise split.  A[i,h] = sum_d (w[h,d]-w[h,16+d])*x[i,d] + b[h]
//                              B[j,h] = sum_d w[h,16+d]*x[j,d]
// relu(A[i,:]+B[j,:]) reconstructs out1[i,j,:] -- the [N,N,H] tensor is never
// materialized (rank-separable linear layer).
// ---------------------------------------------------------------------------
__global__ void proj1_kernel(const float* __restrict__ x, const float* __restrict__ w,
                             const float* __restrict__ bias,
                             float* __restrict__ A, float* __restrict__ B) {
    int idx = blockIdx.x * 256 + threadIdx.x;      // 0..32767
    int i = idx >> 5, h = idx & 31;
    float sa = bias[h];
    float sb = 0.f;
#pragma unroll
    for (int d = 0; d < 16; ++d) {
        float xv = x[i * 16 + d];
        float wa = w[h * 32 + d];
        float wb = w[h * 32 + 16 + d];
        sa += (wa - wb) * xv;
        sb += wb * xv;
    }
    A[i * 32 + h] = sa;
    B[i * 32 + h] = sb;
}

// ---------------------------------------------------------------------------
// K3: stage-2 pairwise split, input h1 [1024,32] fp32, w: [32,64] fp32
// ---------------------------------------------------------------------------
__global__ void proj2_kernel(const float* __restrict__ h1, const float* __restrict__ w,
                             const float* __restrict__ bias,
                             float* __restrict__ A, float* __restrict__ B) {
    int idx = blockIdx.x * 256 + threadIdx.x;      // 0..32767
    int i = idx >> 5, h = idx & 31;
    float sa = bias[h];
    float sb = 0.f;
#pragma unroll
    for (int k = 0; k < 32; ++k) {
        float hv = h1[i * 32 + k];
        float wa = w[h * 64 + k];
        float wb = w[h * 64 + 32 + k];
        sa += (wa - wb) * hv;
        sb += wb * hv;
    }
    A[i * 32 + h] = sa;
    B[i * 32 + h] = sb;
}

// ---------------------------------------------------------------------------
// GRU: ONE WAVE per batch element. Wave-synchronous, no LDS, no barriers.
// seq[b,t,:] = relu(A[b,:] + B[t,:]).  Gate order r,z,n (PyTorch).
//
// Lane l (m = l&31) holds 4 weight rows in VGPRs (128 regs):
//   wA = wih[l]      (r-row for l<32, z-row for l>=32; x-side)
//   wB = whh[l]      (same rows, h-side)
//   wC = wih[64+m]   (n-gate x-side row, replicated in both halves)
//   wD = whh[64+m]   (n-gate h-side row, replicated)
// o and h are wave-uniform 32-vectors broadcast to SGPRs via v_readlane and
// consumed as the scalar operand of v_fmac.  The entire X-phase (o_t+1,
// its broadcast, and both x-side dots) is independent of h and is computed
// during step t's h-critical path (manual software pipeline, distance-2
// global prefetch of the B row).  __launch_bounds__(64,1): 1 wave/SIMD,
// full VGPR budget so all 128 weight values stay register-resident.
// ---------------------------------------------------------------------------
__global__ __launch_bounds__(64, 1) void gru_kernel(
    const float* __restrict__ A, const float* __restrict__ B,
    const float* __restrict__ wih, const float* __restrict__ whh,
    const float* __restrict__ bih, const float* __restrict__ bhh,
    float* __restrict__ h_out) {
    const int b = blockIdx.x;
    const int l = threadIdx.x;        // 0..63
    const int m = l & 31;

    float wA[32], wB[32], wC[32], wD[32];
#pragma unroll
    for (int k = 0; k < 32; ++k) {
        wA[k] = wih[l * 32 + k];
        wB[k] = whh[l * 32 + k];
        wC[k] = wih[(64 + m) * 32 + k];
        wD[k] = whh[(64 + m) * 32 + k];
    }
    const float b1 = bih[l] + bhh[l];      // fused r/z bias (row l)
    const float bx = bih[64 + m];          // n-gate x bias
    const float bh = bhh[64 + m];          // n-gate h bias

    const float a_r = A[b * 32 + m];       // replicated in both halves
    float h_l = 0.f;                       // h_m replicated in both halves
    float hu[32];                          // wave-uniform h -> SGPRs
#pragma unroll
    for (int k = 0; k < 32; ++k) hu[k] = 0.f;

    // X-phase for t=0
    float xg1, xgn;
    {
        float o0 = fmaxf(a_r + B[m], 0.f);
        xg1 = b1; xgn = bx;
#pragma unroll
        for (int k = 0; k < 32; ++k) {
            float ok = rl(o0, k);
            xg1 = fmaf(wA[k], ok, xg1);
            xgn = fmaf(wC[k], ok, xgn);
        }
    }
    float b_next = B[32 + m];              // B row for t=1

#pragma unroll 2
    for (int t = 0; t < 1024; ++t) {
        // prefetch B row t+2 (consumed next iteration; ~1 full step to land)
        float b_pref = B[((t + 2) & 1023) * 32 + m];

        // H-phase: depends on hu (critical chain)
        float hg1 = 0.f, hgn = bh;
#pragma unroll
        for (int k = 0; k < 32; ++k) {
            hg1 = fmaf(wB[k], hu[k], hg1);
            hgn = fmaf(wD[k], hu[k], hgn);
        }

        // X-phase for t+1: fully independent of h, fills latency
        float nxg1 = b1, nxgn = bx;
        {
            float onext = fmaxf(a_r + b_next, 0.f);
#pragma unroll
            for (int k = 0; k < 32; ++k) {
                float ok = rl(onext, k);
                nxg1 = fmaf(wA[k], ok, nxg1);
                nxgn = fmaf(wC[k], ok, nxgn);
            }
        }

        // gates: lane l<32 holds r_m, l>=32 holds z_m
        float sg = 1.f / (1.f + __expf(-(xg1 + hg1)));
        float rr = __shfl(sg, m);          // r_m -> all lanes
        float zz = __shfl(sg, m + 32);     // z_m -> all lanes
        float npre = xgn + rr * hgn;
        float n = 1.f - 2.f / (__expf(2.f * npre) + 1.f);   // tanh
        h_l = (1.f - zz) * n + zz * h_l;

        // broadcast new h for next step
#pragma unroll
        for (int k = 0; k < 32; ++k) hu[k] = rl(h_l, k);

        xg1 = nxg1; xgn = nxgn;
        b_next = b_pref;
    }

    if (l < 32) h_out[b * 32 + m] = h_l;
}

// ---------------------------------------------------------------------------
// K5: classifier. out[i,o] = sum_k clf_w[o,k]*h2[i,k] + clf_b[o]  (fp32 out)
// ---------------------------------------------------------------------------
__global__ void clf_kernel(const float* __restrict__ h2, const float* __restrict__ w,
                           const float* __restrict__ bias, float* __restrict__ out) {
    int idx = blockIdx.x * 256 + threadIdx.x;      // 0..3071
    if (idx >= 3072) return;
    int i = idx / 3, o = idx - i * 3;
    float s = bias[o];
#pragma unroll
    for (int k = 0; k < 32; ++k) s += w[o * 32 + k] * h2[i * 32 + k];
    out[idx] = s;
}

extern "C" void kernel_launch(void* const* d_in, const int* in_sizes, int n_in,
                              void* d_out, int out_size, void* d_ws, size_t ws_size,
                              hipStream_t stream) {
    const float* x       = (const float*)d_in[0];
    const float* p1w     = (const float*)d_in[1];
    const float* p1b     = (const float*)d_in[2];
    const float* g1_wih  = (const float*)d_in[3];
    const float* g1_whh  = (const float*)d_in[4];
    const float* g1_bih  = (const float*)d_in[5];
    const float* g1_bhh  = (const float*)d_in[6];
    const float* p2w     = (const float*)d_in[7];
    const float* p2b     = (const float*)d_in[8];
    const float* g2_wih  = (const float*)d_in[9];
    const float* g2_whh  = (const float*)d_in[10];
    const float* g2_bih  = (const float*)d_in[11];
    const float* g2_bhh  = (const float*)d_in[12];
    const float* clfw    = (const float*)d_in[13];
    const float* clfb    = (const float*)d_in[14];

    // Workspace layout (reused across stages; 3 x 32768 floats = 384 KB):
    float* ws = (float*)d_ws;
    float* A  = ws;              // A1 then A2
    float* Bt = ws + 32768;      // B1 then B2
    float* h  = ws + 65536;      // h1 then h2

    proj1_kernel<<<128, 256, 0, stream>>>(x, p1w, p1b, A, Bt);
    gru_kernel<<<1024, 64, 0, stream>>>(A, Bt, g1_wih, g1_whh, g1_bih, g1_bhh, h);
    proj2_kernel<<<128, 256, 0, stream>>>(h, p2w, p2b, A, Bt);
    gru_kernel<<<1024, 64, 0, stream>>>(A, Bt, g2_wih, g2_whh, g2_bih, g2_bhh, h);
    clf_kernel<<<12, 256, 0, stream>>>(h, clfw, clfb, (float*)d_out);
}

// Round 6
// 764.462 us; speedup vs baseline: 2.1208x; 1.2526x over previous
//
#include <hip/hip_runtime.h>

// N=1024, D=16, H=32, 3H=96.  All tensors fp32 (per reference dtypes).

typedef _Float16 hv2 __attribute__((ext_vector_type(2)));

__device__ __forceinline__ unsigned rlu(unsigned v, int k) {
    return (unsigned)__builtin_amdgcn_readlane((int)v, k);
}
// pack two fp32 -> half2 bits (v_cvt_pkrtz_f16_f32)
__device__ __forceinline__ unsigned pkh(float a, float b) {
    auto t = __builtin_amdgcn_cvt_pkrtz(a, b);   // native return type
    return __builtin_bit_cast(unsigned, t);
}
// dot2: c += a.x*b.x + a.y*b.y   (f16 inputs, f32 accumulate)
#if __has_builtin(__builtin_amdgcn_fdot2)
__device__ __forceinline__ float d2(unsigned a, unsigned b, float c) {
    return __builtin_amdgcn_fdot2(__builtin_bit_cast(hv2, a),
                                  __builtin_bit_cast(hv2, b), c, false);
}
#else
__device__ __forceinline__ float d2(unsigned a, unsigned b, float c) {
    hv2 x = __builtin_bit_cast(hv2, a), y = __builtin_bit_cast(hv2, b);
    return fmaf((float)x.x, (float)y.x, fmaf((float)x.y, (float)y.y, c));
}
#endif
// neighbor value (lane^1) via LDS-crossbar swizzle (1 op, no banks)
__device__ __forceinline__ float swz1(float v) {
    return __int_as_float(__builtin_amdgcn_ds_swizzle(__float_as_int(v), 0x041F));
}

// ---------------------------------------------------------------------------
// K1: stage-1 pairwise split.  A[i,h] = sum_d (w[h,d]-w[h,16+d])*x[i,d] + b[h]
//                              B[j,h] = sum_d w[h,16+d]*x[j,d]
// relu(A[i,:]+B[j,:]) reconstructs out1[i,j,:] -- [N,N,H] never materialized.
// ---------------------------------------------------------------------------
__global__ void proj1_kernel(const float* __restrict__ x, const float* __restrict__ w,
                             const float* __restrict__ bias,
                             float* __restrict__ A, float* __restrict__ B) {
    int idx = blockIdx.x * 256 + threadIdx.x;      // 0..32767
    int i = idx >> 5, h = idx & 31;
    float sa = bias[h];
    float sb = 0.f;
#pragma unroll
    for (int d = 0; d < 16; ++d) {
        float xv = x[i * 16 + d];
        float wa = w[h * 32 + d];
        float wb = w[h * 32 + 16 + d];
        sa += (wa - wb) * xv;
        sb += wb * xv;
    }
    A[i * 32 + h] = sa;
    B[i * 32 + h] = sb;
}

__global__ void proj2_kernel(const float* __restrict__ h1, const float* __restrict__ w,
                             const float* __restrict__ bias,
                             float* __restrict__ A, float* __restrict__ B) {
    int idx = blockIdx.x * 256 + threadIdx.x;      // 0..32767
    int i = idx >> 5, h = idx & 31;
    float sa = bias[h];
    float sb = 0.f;
#pragma unroll
    for (int k = 0; k < 32; ++k) {
        float hv = h1[i * 32 + k];
        float wa = w[h * 64 + k];
        float wb = w[h * 64 + 32 + k];
        sa += (wa - wb) * hv;
        sb += wb * hv;
    }
    A[i * 32 + h] = sa;
    B[i * 32 + h] = sb;
}

// ---------------------------------------------------------------------------
// GRU: ONE WAVE per batch element, wave-synchronous, no barriers.
// seq[b,t,:] = relu(A[b,:] + B[t,:]).  Gate order r,z,n (PyTorch).
// f16-packed weights (half2 in 16 uints per row -> 64 VGPRs total), dots via
// v_dot2_f32_f16 with SGPR-broadcast operands.  o/h broadcast: pair-pack via
// ds_swizzle(xor1)+cvt_pkrtz, then 16 readlanes each.  X-phase of step t+1
// overlaps step t's h-critical path (software pipeline, dist-2 B prefetch).
// ---------------------------------------------------------------------------
__global__ __launch_bounds__(64, 1) void gru_kernel(
    const float* __restrict__ A, const float* __restrict__ B,
    const float* __restrict__ wih, const float* __restrict__ whh,
    const float* __restrict__ bih, const float* __restrict__ bhh,
    float* __restrict__ h_out) {
    const int b = blockIdx.x;
    const int l = threadIdx.x;        // 0..63
    const int m = l & 31;

    // packed weight rows:
    //   wA2 = wih[l]    (r-row l<32 / z-row l>=32, x-side)
    //   wB2 = whh[l]    (same rows, h-side)
    //   wC2 = wih[64+m] (n-gate x-side, replicated both halves)
    //   wD2 = whh[64+m] (n-gate h-side, replicated)
    unsigned wA2[16], wB2[16], wC2[16], wD2[16];
#pragma unroll
    for (int k = 0; k < 16; ++k) {
        wA2[k] = pkh(wih[l * 32 + 2 * k], wih[l * 32 + 2 * k + 1]);
        wB2[k] = pkh(whh[l * 32 + 2 * k], whh[l * 32 + 2 * k + 1]);
        wC2[k] = pkh(wih[(64 + m) * 32 + 2 * k], wih[(64 + m) * 32 + 2 * k + 1]);
        wD2[k] = pkh(whh[(64 + m) * 32 + 2 * k], whh[(64 + m) * 32 + 2 * k + 1]);
    }
    const float b1 = bih[l] + bhh[l];      // fused r/z bias (row l)
    const float bx = bih[64 + m];          // n-gate x bias
    const float bh = bhh[64 + m];          // n-gate h bias

    const float a_r = A[b * 32 + m];       // replicated in both halves
    float h_l = 0.f;                       // h_m replicated in both halves

    unsigned hu2[16];                      // wave-uniform packed h -> SGPRs
#pragma unroll
    for (int k = 0; k < 16; ++k) hu2[k] = 0u;

    // X-phase for t=0
    float xg1, xgn;
    {
        float o0 = fmaxf(a_r + B[m], 0.f);
        unsigned opk = pkh(o0, swz1(o0));  // even lanes: (o_2k, o_2k+1)
        xg1 = b1; xgn = bx;
#pragma unroll
        for (int k = 0; k < 16; ++k) {
            unsigned ok = rlu(opk, 2 * k);
            xg1 = d2(wA2[k], ok, xg1);
            xgn = d2(wC2[k], ok, xgn);
        }
    }
    float b_next = B[32 + m];              // B row for t=1

#pragma unroll 2
    for (int t = 0; t < 1024; ++t) {
        // prefetch B row t+2 (consumed next iteration)
        float b_pref = B[((t + 2) & 1023) * 32 + m];

        // H-phase: depends on hu2 (critical chain), two interleaved chains
        float hg1 = 0.f, hgn = bh;
#pragma unroll
        for (int k = 0; k < 16; ++k) {
            hg1 = d2(wB2[k], hu2[k], hg1);
            hgn = d2(wD2[k], hu2[k], hgn);
        }

        // X-phase for t+1: independent of h, fills latency
        float nxg1 = b1, nxgn = bx;
        {
            float onext = fmaxf(a_r + b_next, 0.f);
            unsigned opk = pkh(onext, swz1(onext));
#pragma unroll
            for (int k = 0; k < 16; ++k) {
                unsigned ok = rlu(opk, 2 * k);
                nxg1 = d2(wA2[k], ok, nxg1);
                nxgn = d2(wC2[k], ok, nxgn);
            }
        }

        // gates: lane l<32 holds r_m, l>=32 holds z_m
        float sg = 1.f / (1.f + __expf(-(xg1 + hg1)));
        float rr = __shfl(sg, m);          // r_m -> all lanes
        float zz = __shfl(sg, m + 32);     // z_m -> all lanes
        float npre = xgn + rr * hgn;
        float n = 1.f - 2.f / (__expf(2.f * npre) + 1.f);   // tanh
        h_l = (1.f - zz) * n + zz * h_l;

        // broadcast new h (pair-packed, 16 readlanes)
        unsigned hpk = pkh(h_l, swz1(h_l));
#pragma unroll
        for (int k = 0; k < 16; ++k) hu2[k] = rlu(hpk, 2 * k);

        xg1 = nxg1; xgn = nxgn;
        b_next = b_pref;
    }

    if (l < 32) h_out[b * 32 + m] = h_l;
}

// ---------------------------------------------------------------------------
// K5: classifier. out[i,o] = sum_k clf_w[o,k]*h2[i,k] + clf_b[o]  (fp32 out)
// ---------------------------------------------------------------------------
__global__ void clf_kernel(const float* __restrict__ h2v, const float* __restrict__ w,
                           const float* __restrict__ bias, float* __restrict__ out) {
    int idx = blockIdx.x * 256 + threadIdx.x;      // 0..3071
    if (idx >= 3072) return;
    int i = idx / 3, o = idx - i * 3;
    float s = bias[o];
#pragma unroll
    for (int k = 0; k < 32; ++k) s += w[o * 32 + k] * h2v[i * 32 + k];
    out[idx] = s;
}

extern "C" void kernel_launch(void* const* d_in, const int* in_sizes, int n_in,
                              void* d_out, int out_size, void* d_ws, size_t ws_size,
                              hipStream_t stream) {
    const float* x       = (const float*)d_in[0];
    const float* p1w     = (const float*)d_in[1];
    const float* p1b     = (const float*)d_in[2];
    const float* g1_wih  = (const float*)d_in[3];
    const float* g1_whh  = (const float*)d_in[4];
    const float* g1_bih  = (const float*)d_in[5];
    const float* g1_bhh  = (const float*)d_in[6];
    const float* p2w     = (const float*)d_in[7];
    const float* p2b     = (const float*)d_in[8];
    const float* g2_wih  = (const float*)d_in[9];
    const float* g2_whh  = (const float*)d_in[10];
    const float* g2_bih  = (const float*)d_in[11];
    const float* g2_bhh  = (const float*)d_in[12];
    const float* clfw    = (const float*)d_in[13];
    const float* clfb    = (const float*)d_in[14];

    // Workspace layout (reused across stages; 3 x 32768 floats = 384 KB):
    float* ws = (float*)d_ws;
    float* A  = ws;              // A1 then A2
    float* Bt = ws + 32768;      // B1 then B2
    float* h  = ws + 65536;      // h1 then h2

    proj1_kernel<<<128, 256, 0, stream>>>(x, p1w, p1b, A, Bt);
    gru_kernel<<<1024, 64, 0, stream>>>(A, Bt, g1_wih, g1_whh, g1_bih, g1_bhh, h);
    proj2_kernel<<<128, 256, 0, stream>>>(h, p2w, p2b, A, Bt);
    gru_kernel<<<1024, 64, 0, stream>>>(A, Bt, g2_wih, g2_whh, g2_bih, g2_bhh, h);
    clf_kernel<<<12, 256, 0, stream>>>(h, clfw, clfb, (float*)d_out);
}